// Round 2
// baseline (4717.119 us; speedup 1.0000x reference)
//
#include <hip/hip_runtime.h>
#include <float.h>

#define NEMB 1024
#define EDIM 256
#define BM   64
#define HW   4096   // 64*64
#define NT   1024   // threads/block: 16 waves share one 64 KiB z tile
#define NW   (NT / 64)
#define ZQ_ELEMS 33554432   // 32*256*4096

// numpy FLOAT_pairwise_sum of squares, n=256: two 128-blocks, 8 accumulators
// r[j] += a[8i+j], tree-combine ((r0+r1)+(r2+r3))+((r4+r5)+(r6+r7)), then
// blk0+blk1. Squares rounded separately (contract off).
template <typename F>
__device__ __forceinline__ float np_sumsq_256(F get) {
#pragma clang fp contract(off)
    float blk[2];
#pragma unroll
    for (int h = 0; h < 2; ++h) {
        const int base = h * 128;
        float r[8];
#pragma unroll
        for (int j = 0; j < 8; ++j) {
            float v = get(base + j);
            r[j] = v * v;
        }
        for (int i = 8; i < 128; i += 8) {
#pragma unroll
            for (int j = 0; j < 8; ++j) {
                float v = get(base + i + j);
                float p = v * v;
                r[j] = r[j] + p;
            }
        }
        blk[h] = ((r[0] + r[1]) + (r[2] + r[3])) + ((r[4] + r[5]) + (r[6] + r[7]));
    }
    return blk[0] + blk[1];
}

__global__ __launch_bounds__(256) void esq_kernel(const float* __restrict__ emb,
                                                  float* __restrict__ esq) {
    int n = blockIdx.x * 256 + threadIdx.x;
    const float* e = emb + (size_t)n * EDIM;
    esq[n] = np_sumsq_256([&](int k) { return e[k]; });
}

// z tile, PAIR-INTERLEAVED: value z(k,r) at word (k>>1)*128 + 2*r + (k&1).
// Lane r reads float2 {z(2m,r), z(2m+1,r)} at word m*128+2r: the 64 lanes
// cover words [m*128, m*128+128) exactly -> conflict-free ds_read_b64.
//
// Main loop: acc[64] = the wave's FULL codeword quota, so z is read from LDS
// exactly once (4x fewer ds_reads than the grouped NB=16 version), in
// double-buffered 16-k register chunks. Between ds_read batches there are
// 1024 FMAs (~2048 cyc) touching only SGPR emb (s_load) + VGPRs, so the
// compiler's lgkmcnt waits are clean end-of-window SMEM drains with a full
// compute block of issue-ahead distance (the previous structure forced
// lgkmcnt(0) every 8-k half-chunk, draining just-issued prefetches and
// exposing scalar-cache miss latency every ~128 cycles).
__global__ __launch_bounds__(NT, 4) void vq_kernel(const float* __restrict__ z,
                                                   const float* __restrict__ emb,
                                                   const float* __restrict__ esq,
                                                   float* __restrict__ out) {
    __shared__ float zl[BM * EDIM];   // 64 KiB

    const int t   = threadIdx.x;
    const int blk = blockIdx.x;           // 2048 blocks: 64 per batch image
    const int b   = blk >> 6;
    const int hw0 = (blk & 63) * BM;
    const float* zbase = z + (size_t)b * EDIM * HW;

    // ---- stage z tile: 4096 float4, 4 per thread, coalesced along hw ----
#pragma unroll
    for (int pass = 0; pass < 4; ++pass) {
        int f4 = pass * NT + t;
        int r4 = (f4 & 15) * 4;
        int k  = f4 >> 4;
        float4 v = *(const float4*)(zbase + (size_t)k * HW + hw0 + r4);
        int w = (k >> 1) * 128 + 2 * r4 + (k & 1);
        zl[w + 0] = v.x;
        zl[w + 2] = v.y;
        zl[w + 4] = v.z;
        zl[w + 6] = v.w;
    }
    __syncthreads();

    const int r = t & 63;                 // my row (lane id)
    const float* zr = zl + 2 * r;         // lane's row base in interleaved tile
    // z_sq with exact numpy pairwise semantics (redundant per wave; cheap)
    const float zsq = np_sumsq_256([&](int k) { return zr[(k >> 1) * 128 + (k & 1)]; });

    // wave id -> 64-codeword range (uniform -> scalar emb loads)
    const int q  = __builtin_amdgcn_readfirstlane(t >> 6);
    const int n0 = q * 64;

    float acc[64];
#pragma unroll
    for (int n = 0; n < 64; ++n) acc[n] = 0.f;

    // 16-k register chunks of z, double-buffered across iterations
    float2 zA[8], zB[8];
    auto ldz = [&](float2* dst, int kbase) {
        const int m0 = kbase >> 1;
#pragma unroll
        for (int u = 0; u < 8; ++u)
            dst[u] = *(const float2*)(zr + (m0 + u) * 128);
    };
    // e_z: strictly sequential fp32 FMA over k=0..255 per codeword (chunk-
    // ascending, pair-ascending, .x before .y) — bit-identical to the numpy
    // microkernel order. er chunk is 64 B -> one s_load_dwordx16 per n.
    auto fmablk = [&](const float2* zc, int kbase) {
#pragma unroll
        for (int n = 0; n < 64; ++n) {
            const float* er = emb + (size_t)(n0 + n) * EDIM + kbase;
            float a = acc[n];
#pragma unroll
            for (int u = 0; u < 8; ++u) {
                a = fmaf(zc[u].x, er[2 * u + 0], a);
                a = fmaf(zc[u].y, er[2 * u + 1], a);
            }
            acc[n] = a;
        }
    };

    ldz(zA, 0);
#pragma unroll 1
    for (int c = 0; c < 8; ++c) {
        const int k0 = c * 32;
        ldz(zB, k0 + 16);            // prefetch odd chunk
        fmablk(zA, k0);              // 1024 FMAs, SMEM-only lgkm inside
        if (c < 7) ldz(zA, k0 + 32); // prefetch next even chunk
        fmablk(zB, k0 + 16);
    }

    float best = FLT_MAX;
    int   bidx = 0;
#pragma unroll
    for (int n = 0; n < 64; ++n) {
        // numpy: dist = RN( RN(zsq+esq) - 2*ez ); 2*ez exact -> fma form
        // is bit-identical.
        float t1 = zsq + esq[n0 + n];
        float d  = fmaf(-2.f, acc[n], t1);
        if (d < best) { best = d; bidx = n0 + n; }   // strict <: first-index
    }

    // ---- cross-wave (min,idx) reduction, reusing zl ----
    __syncthreads();                        // all zl reads done
    float* rv   = zl;                       // [1024] best value
    int*   ri   = (int*)(zl + NT);          // [1024] best idx
    int*   ifin = (int*)(zl + 2 * NT);      // [64]   final idx per row
    rv[t] = best;
    ri[t] = bidx;
    __syncthreads();
    if (t < 64) {
        float bv = rv[t];
        int   bi = ri[t];
#pragma unroll
        for (int w = 1; w < NW; ++w) {
            float v = rv[t + 64 * w];
            int   i = ri[t + 64 * w];
            // waves cover ascending idx ranges; strict < keeps lowest idx
            if (v < bv) { bv = v; bi = i; }
        }
        ifin[t] = bi;
        out[(size_t)ZQ_ELEMS + (size_t)blk * BM + t] = (float)bi;  // idx as float
    }
    __syncthreads();

    // ---- z_q[b][c][hw] = emb[idx[hw]][c], coalesced float4 along hw ----
    float* zq = out + (size_t)b * EDIM * HW;
#pragma unroll
    for (int pass = 0; pass < 4; ++pass) {
        int f4 = pass * NT + t;
        int r4 = (f4 & 15) * 4;
        int c  = f4 >> 4;
        float4 v;
        v.x = emb[(size_t)ifin[r4 + 0] * EDIM + c];
        v.y = emb[(size_t)ifin[r4 + 1] * EDIM + c];
        v.z = emb[(size_t)ifin[r4 + 2] * EDIM + c];
        v.w = emb[(size_t)ifin[r4 + 3] * EDIM + c];
        *(float4*)(zq + (size_t)c * HW + hw0 + r4) = v;
    }
}

extern "C" void kernel_launch(void* const* d_in, const int* in_sizes, int n_in,
                              void* d_out, int out_size, void* d_ws, size_t ws_size,
                              hipStream_t stream) {
    const float* z   = (const float*)d_in[0];   // [32,256,64,64]
    const float* emb = (const float*)d_in[1];   // [1024,256]
    float* out = (float*)d_out;                 // 33554432 z_q + 131072 idx (as float)
    float* esq = (float*)d_ws;                  // 1024 floats scratch

    esq_kernel<<<NEMB / 256, 256, 0, stream>>>(emb, esq);
    vq_kernel<<<131072 / BM, NT, 0, stream>>>(z, emb, esq, out);
}

// Round 4
// 1186.799 us; speedup vs baseline: 3.9747x; 3.9747x over previous
//
#include <hip/hip_runtime.h>
#include <float.h>

#define NEMB 1024
#define EDIM 256
#define BM   128    // rows per block (z tile); 2 rows per lane
#define HW   4096   // 64*64
#define NT   1024   // 16 waves
#define NW   (NT / 64)
#define NB   8
#define ZQ_ELEMS 33554432   // 32*256*4096

// numpy FLOAT_pairwise_sum of squares, n=256: two 128-blocks, 8 accumulators
// r[j] += a[8i+j], tree-combine ((r0+r1)+(r2+r3))+((r4+r5)+(r6+r7)), then
// blk0+blk1. Squares rounded separately (contract off).
template <typename F>
__device__ __forceinline__ float np_sumsq_256(F get) {
#pragma clang fp contract(off)
    float blk[2];
#pragma unroll
    for (int h = 0; h < 2; ++h) {
        const int base = h * 128;
        float r[8];
#pragma unroll
        for (int j = 0; j < 8; ++j) {
            float v = get(base + j);
            r[j] = v * v;
        }
        for (int i = 8; i < 128; i += 8) {
#pragma unroll
            for (int j = 0; j < 8; ++j) {
                float v = get(base + i + j);
                float p = v * v;
                r[j] = r[j] + p;
            }
        }
        blk[h] = ((r[0] + r[1]) + (r[2] + r[3])) + ((r[4] + r[5]) + (r[6] + r[7]));
    }
    return blk[0] + blk[1];
}

__global__ __launch_bounds__(256) void esq_kernel(const float* __restrict__ emb,
                                                  float* __restrict__ esq) {
    int n = blockIdx.x * 256 + threadIdx.x;
    const float* e = emb + (size_t)n * EDIM;
    esq[n] = np_sumsq_256([&](int k) { return e[k]; });
}

// z tile, PAIR-INTERLEAVED over 128 rows: z(k,row) at word
// (k>>1)*256 + 2*row + (k&1). Lane r owns rows r and r+64; its two
// ds_read_b64 per k-pair land in word ranges [m*256, m*256+128) and
// [m*256+128, m*256+256) -> conflict-free.
//
// KEY CHANGE (scalar-wall theory): 2 rows per lane means every s_load'ed
// emb value feeds 2 FMAs instead of 1. Rounds 0/1 both pinned at the same
// absolute scalar-fetch rate (~2.8 B/cy/CU, 32 waves streaming disjoint
// 64 KiB emb ranges through the per-CU scalar cache) with FMA issue stuck
// at 35%; halving bytes-per-FMA directly attacks that wall. Register
// budget kept ~62 live VGPRs (round-2 lesson: demand near/over the cap ->
// catastrophic scratch spill).
__global__ __launch_bounds__(NT, 4) void vq_kernel(const float* __restrict__ z,
                                                   const float* __restrict__ emb,
                                                   const float* __restrict__ esq,
                                                   float* __restrict__ out) {
    __shared__ float zl[BM * EDIM];   // 128 KiB -> 1 block/CU, 16 waves/CU

    const int t   = threadIdx.x;
    const int blk = blockIdx.x;           // 1024 blocks: 32 per batch image
    const int b   = blk >> 5;
    const int hw0 = (blk & 31) * BM;
    const float* zbase = z + (size_t)b * EDIM * HW;

    // ---- stage z tile: 8192 float4, 8 per thread, coalesced along hw ----
#pragma unroll
    for (int pass = 0; pass < 8; ++pass) {
        int f4 = pass * NT + t;
        int r4 = (f4 & 31) * 4;
        int k  = f4 >> 5;
        float4 v = *(const float4*)(zbase + (size_t)k * HW + hw0 + r4);
        int w = (k >> 1) * 256 + 2 * r4 + (k & 1);
        zl[w + 0] = v.x;
        zl[w + 2] = v.y;
        zl[w + 4] = v.z;
        zl[w + 6] = v.w;
    }
    __syncthreads();

    const int r = t & 63;                 // lane id; owns rows r and r+64
    const float* zr = zl + 2 * r;
    // z_sq with exact numpy pairwise semantics (redundant per wave; cheap)
    const float zsq0 = np_sumsq_256([&](int k) { return zr[(k >> 1) * 256 + (k & 1)]; });
    const float zsq1 = np_sumsq_256([&](int k) { return zr[(k >> 1) * 256 + 128 + (k & 1)]; });

    // wave id -> 64-codeword quota (uniform -> scalar emb loads)
    const int q = __builtin_amdgcn_readfirstlane(t >> 6);

    float best0 = FLT_MAX, best1 = FLT_MAX;
    int   bidx0 = 0,       bidx1 = 0;

#pragma unroll 1
    for (int g = 0; g < 8; ++g) {
        const int n0 = q * 64 + g * NB;
        float acc0[NB], acc1[NB];
#pragma unroll
        for (int j = 0; j < NB; ++j) { acc0[j] = 0.f; acc1[j] = 0.f; }

        // 8-k register chunks of z (both rows), double-buffered
        float2 zA[8], zB[8];   // [0..3] row r, [4..7] row r+64
        auto ldz = [&](float2* dst, int kbase) {
            const int m0 = kbase >> 1;
#pragma unroll
            for (int u = 0; u < 4; ++u) {
                dst[u]     = *(const float2*)(zr + (m0 + u) * 256);
                dst[4 + u] = *(const float2*)(zr + (m0 + u) * 256 + 128);
            }
        };
        // e_z: strictly sequential fp32 FMA over k per codeword per row
        // (chunk-ascending, pair-ascending, .x before .y) — bit-identical
        // numpy microkernel order. er chunk is 32 B -> s_load_dwordx8 per n.
        auto fma8 = [&](const float2* zc, int kbase) {
#pragma unroll
            for (int j = 0; j < NB; ++j) {
                const float* er = emb + (size_t)(n0 + j) * EDIM + kbase;
                float a0 = acc0[j], a1 = acc1[j];
#pragma unroll
                for (int u = 0; u < 4; ++u) {
                    a0 = fmaf(zc[u].x, er[2 * u + 0], a0);
                    a0 = fmaf(zc[u].y, er[2 * u + 1], a0);
                }
#pragma unroll
                for (int u = 0; u < 4; ++u) {
                    a1 = fmaf(zc[4 + u].x, er[2 * u + 0], a1);
                    a1 = fmaf(zc[4 + u].y, er[2 * u + 1], a1);
                }
                acc0[j] = a0; acc1[j] = a1;
            }
        };

        ldz(zA, 0);
        for (int k = 0; k < EDIM; k += 16) {
            ldz(zB, k + 8);
            fma8(zA, k);
            if (k + 16 < EDIM) ldz(zA, k + 16);
            fma8(zB, k + 8);
        }

#pragma unroll
        for (int j = 0; j < NB; ++j) {
            // numpy: dist = RN( RN(zsq+esq) - 2*ez ); 2*ez exact -> fma form
            // is bit-identical.
            float es = esq[n0 + j];
            float t1 = zsq0 + es;
            float d  = fmaf(-2.f, acc0[j], t1);
            if (d < best0) { best0 = d; bidx0 = n0 + j; }   // strict <
            float t2 = zsq1 + es;
            float d2 = fmaf(-2.f, acc1[j], t2);
            if (d2 < best1) { best1 = d2; bidx1 = n0 + j; }
        }
    }

    // ---- cross-wave (min,idx) reduction, reusing zl ----
    __syncthreads();                        // all zl reads done
    float* rv   = zl;                       // [NW*BM] best value
    int*   ri   = (int*)(zl + NW * BM);     // [NW*BM] best idx
    int*   ifin = (int*)(zl + 2 * NW * BM); // [BM]    final idx per row
    rv[q * BM + r]      = best0;
    rv[q * BM + r + 64] = best1;
    ri[q * BM + r]      = bidx0;
    ri[q * BM + r + 64] = bidx1;
    __syncthreads();
    if (t < BM) {
        float bv = rv[t];
        int   bi = ri[t];
#pragma unroll
        for (int w = 1; w < NW; ++w) {
            float v = rv[w * BM + t];
            int   i = ri[w * BM + t];
            // waves cover ascending idx ranges; strict < keeps lowest idx
            if (v < bv) { bv = v; bi = i; }
        }
        ifin[t] = bi;
        out[(size_t)ZQ_ELEMS + (size_t)blk * BM + t] = (float)bi;  // idx as float
    }
    __syncthreads();

    // ---- z_q[b][c][hw] = emb[idx[hw]][c], coalesced float4 along hw ----
    float* zq = out + (size_t)b * EDIM * HW;
#pragma unroll
    for (int pass = 0; pass < 8; ++pass) {
        int f4 = pass * NT + t;
        int r4 = (f4 & 31) * 4;
        int c  = f4 >> 5;
        float4 v;
        v.x = emb[(size_t)ifin[r4 + 0] * EDIM + c];
        v.y = emb[(size_t)ifin[r4 + 1] * EDIM + c];
        v.z = emb[(size_t)ifin[r4 + 2] * EDIM + c];
        v.w = emb[(size_t)ifin[r4 + 3] * EDIM + c];
        *(float4*)(zq + (size_t)c * HW + hw0 + r4) = v;
    }
}

extern "C" void kernel_launch(void* const* d_in, const int* in_sizes, int n_in,
                              void* d_out, int out_size, void* d_ws, size_t ws_size,
                              hipStream_t stream) {
    const float* z   = (const float*)d_in[0];   // [32,256,64,64]
    const float* emb = (const float*)d_in[1];   // [1024,256]
    float* out = (float*)d_out;                 // 33554432 z_q + 131072 idx (as float)
    float* esq = (float*)d_ws;                  // 1024 floats scratch

    esq_kernel<<<NEMB / 256, 256, 0, stream>>>(emb, esq);
    vq_kernel<<<131072 / BM, NT, 0, stream>>>(z, emb, esq, out);
}

// Round 5
// 1165.957 us; speedup vs baseline: 4.0457x; 1.0179x over previous
//
#include <hip/hip_runtime.h>
#include <float.h>

#define NEMB 1024
#define EDIM 256
#define BM   128    // rows per block (z tile); 2 rows per lane
#define HW   4096   // 64*64
#define NT   1024   // 16 waves
#define NW   (NT / 64)
#define NB   16     // codewords per accumulator group (LDS bytes/FMA halved vs 8)
#define ZQ_ELEMS 33554432   // 32*256*4096

// numpy FLOAT_pairwise_sum of squares, n=256: two 128-blocks, 8 accumulators
// r[j] += a[8i+j], tree-combine ((r0+r1)+(r2+r3))+((r4+r5)+(r6+r7)), then
// blk0+blk1. Squares rounded separately (contract off).
template <typename F>
__device__ __forceinline__ float np_sumsq_256(F get) {
#pragma clang fp contract(off)
    float blk[2];
#pragma unroll
    for (int h = 0; h < 2; ++h) {
        const int base = h * 128;
        float r[8];
#pragma unroll
        for (int j = 0; j < 8; ++j) {
            float v = get(base + j);
            r[j] = v * v;
        }
        for (int i = 8; i < 128; i += 8) {
#pragma unroll
            for (int j = 0; j < 8; ++j) {
                float v = get(base + i + j);
                float p = v * v;
                r[j] = r[j] + p;
            }
        }
        blk[h] = ((r[0] + r[1]) + (r[2] + r[3])) + ((r[4] + r[5]) + (r[6] + r[7]));
    }
    return blk[0] + blk[1];
}

__global__ __launch_bounds__(256) void esq_kernel(const float* __restrict__ emb,
                                                  float* __restrict__ esq) {
    int n = blockIdx.x * 256 + threadIdx.x;
    const float* e = emb + (size_t)n * EDIM;
    esq[n] = np_sumsq_256([&](int k) { return e[k]; });
}

// z tile, PAIR-INTERLEAVED over 128 rows: z(k,row) at word
// (k>>1)*256 + 2*row + (k&1). Lane r owns rows r and r+64; each ds_read_b64
// covers dwords {2r,2r+1} over a 128-dword segment -> 4 dwords/bank = the
// wave64-b64 floor -> conflict-free.
//
// ROUND-5 CHANGE (LDS-contention theory): R1 and R4 both ran 32 B of LDS
// read per FMA-instr = ~75% duty on the measured ~85 B/cy LDS pipe at full
// FMA rate — a shared-pipe load that stalls all 4 waves/SIMD together
// (per-wave latency would be hidden by multithreading; pipe contention is
// not). NB=16 makes one z register chunk feed 16 codewords -> 16 B/FMA
// (~38% duty). VGPR budget audited (R2 scar): acc 32 + z dbuf 16 (4-k
// chunks) + misc ~14 = ~62 live.
__global__ __launch_bounds__(NT, 4) void vq_kernel(const float* __restrict__ z,
                                                   const float* __restrict__ emb,
                                                   const float* __restrict__ esq,
                                                   float* __restrict__ out) {
    __shared__ float zl[BM * EDIM];   // 128 KiB -> 1 block/CU, 16 waves/CU

    const int t   = threadIdx.x;
    const int blk = blockIdx.x;           // 1024 blocks: 32 per batch image
    const int b   = blk >> 5;
    const int hw0 = (blk & 31) * BM;
    const float* zbase = z + (size_t)b * EDIM * HW;

    // ---- stage z tile: 8192 float4, 8 per thread, coalesced along hw ----
#pragma unroll
    for (int pass = 0; pass < 8; ++pass) {
        int f4 = pass * NT + t;
        int r4 = (f4 & 31) * 4;
        int k  = f4 >> 5;
        float4 v = *(const float4*)(zbase + (size_t)k * HW + hw0 + r4);
        int w = (k >> 1) * 256 + 2 * r4 + (k & 1);
        zl[w + 0] = v.x;
        zl[w + 2] = v.y;
        zl[w + 4] = v.z;
        zl[w + 6] = v.w;
    }
    __syncthreads();

    const int r = t & 63;                 // lane id; owns rows r and r+64
    const float* zr = zl + 2 * r;
    // z_sq with exact numpy pairwise semantics (redundant per wave; cheap)
    const float zsq0 = np_sumsq_256([&](int k) { return zr[(k >> 1) * 256 + (k & 1)]; });
    const float zsq1 = np_sumsq_256([&](int k) { return zr[(k >> 1) * 256 + 128 + (k & 1)]; });

    // wave id -> 64-codeword quota (uniform -> scalar emb loads)
    const int q = __builtin_amdgcn_readfirstlane(t >> 6);

    float best0 = FLT_MAX, best1 = FLT_MAX;
    int   bidx0 = 0,       bidx1 = 0;

#pragma unroll 1
    for (int g = 0; g < 4; ++g) {
        const int n0 = q * 64 + g * NB;
        float acc0[NB], acc1[NB];
#pragma unroll
        for (int j = 0; j < NB; ++j) { acc0[j] = 0.f; acc1[j] = 0.f; }

        // 4-k register chunks of z (both rows), double-buffered.
        // dst[0..1]: row r, k-pairs m0,m0+1; dst[2..3]: row r+64.
        float2 zA[4], zB[4];
        auto ldz = [&](float2* dst, int kbase) {
            const int m0 = kbase >> 1;
            dst[0] = *(const float2*)(zr + (m0 + 0) * 256);
            dst[1] = *(const float2*)(zr + (m0 + 1) * 256);
            dst[2] = *(const float2*)(zr + (m0 + 0) * 256 + 128);
            dst[3] = *(const float2*)(zr + (m0 + 1) * 256 + 128);
        };
        // e_z: strictly sequential fp32 FMA over k per codeword per row
        // (chunk-ascending, pair-ascending, .x before .y) — bit-identical
        // numpy microkernel order. er chunk is 16 B -> s_load_dwordx4 per n.
        auto fma16 = [&](const float2* zc, int kbase) {
#pragma unroll
            for (int j = 0; j < NB; ++j) {
                const float* er = emb + (size_t)(n0 + j) * EDIM + kbase;
                float a0 = acc0[j], a1 = acc1[j];
                a0 = fmaf(zc[0].x, er[0], a0);
                a0 = fmaf(zc[0].y, er[1], a0);
                a0 = fmaf(zc[1].x, er[2], a0);
                a0 = fmaf(zc[1].y, er[3], a0);
                a1 = fmaf(zc[2].x, er[0], a1);
                a1 = fmaf(zc[2].y, er[1], a1);
                a1 = fmaf(zc[3].x, er[2], a1);
                a1 = fmaf(zc[3].y, er[3], a1);
                acc0[j] = a0; acc1[j] = a1;
            }
        };

        ldz(zA, 0);
        for (int k = 0; k < EDIM; k += 8) {
            ldz(zB, k + 4);
            fma16(zA, k);
            if (k + 8 < EDIM) ldz(zA, k + 8);
            fma16(zB, k + 4);
        }

#pragma unroll
        for (int j = 0; j < NB; ++j) {
            // numpy: dist = RN( RN(zsq+esq) - 2*ez ); 2*ez exact -> fma form
            // is bit-identical.
            float es = esq[n0 + j];
            float t1 = zsq0 + es;
            float d  = fmaf(-2.f, acc0[j], t1);
            if (d < best0) { best0 = d; bidx0 = n0 + j; }   // strict <
            float t2 = zsq1 + es;
            float d2 = fmaf(-2.f, acc1[j], t2);
            if (d2 < best1) { best1 = d2; bidx1 = n0 + j; }
        }
    }

    // ---- cross-wave (min,idx) reduction, reusing zl ----
    __syncthreads();                        // all zl reads done
    float* rv   = zl;                       // [NW*BM] best value
    int*   ri   = (int*)(zl + NW * BM);     // [NW*BM] best idx
    int*   ifin = (int*)(zl + 2 * NW * BM); // [BM]    final idx per row
    rv[q * BM + r]      = best0;
    rv[q * BM + r + 64] = best1;
    ri[q * BM + r]      = bidx0;
    ri[q * BM + r + 64] = bidx1;
    __syncthreads();
    if (t < BM) {
        float bv = rv[t];
        int   bi = ri[t];
#pragma unroll
        for (int w = 1; w < NW; ++w) {
            float v = rv[w * BM + t];
            int   i = ri[w * BM + t];
            // waves cover ascending idx ranges; strict < keeps lowest idx
            if (v < bv) { bv = v; bi = i; }
        }
        ifin[t] = bi;
        out[(size_t)ZQ_ELEMS + (size_t)blk * BM + t] = (float)bi;  // idx as float
    }
    __syncthreads();

    // ---- z_q[b][c][hw] = emb[idx[hw]][c], coalesced float4 along hw ----
    float* zq = out + (size_t)b * EDIM * HW;
#pragma unroll
    for (int pass = 0; pass < 8; ++pass) {
        int f4 = pass * NT + t;
        int r4 = (f4 & 31) * 4;
        int c  = f4 >> 5;
        float4 v;
        v.x = emb[(size_t)ifin[r4 + 0] * EDIM + c];
        v.y = emb[(size_t)ifin[r4 + 1] * EDIM + c];
        v.z = emb[(size_t)ifin[r4 + 2] * EDIM + c];
        v.w = emb[(size_t)ifin[r4 + 3] * EDIM + c];
        *(float4*)(zq + (size_t)c * HW + hw0 + r4) = v;
    }
}

extern "C" void kernel_launch(void* const* d_in, const int* in_sizes, int n_in,
                              void* d_out, int out_size, void* d_ws, size_t ws_size,
                              hipStream_t stream) {
    const float* z   = (const float*)d_in[0];   // [32,256,64,64]
    const float* emb = (const float*)d_in[1];   // [1024,256]
    float* out = (float*)d_out;                 // 33554432 z_q + 131072 idx (as float)
    float* esq = (float*)d_ws;                  // 1024 floats scratch

    esq_kernel<<<NEMB / 256, 256, 0, stream>>>(emb, esq);
    vq_kernel<<<131072 / BM, NT, 0, stream>>>(z, emb, esq, out);
}